// Round 1
// baseline (1218.350 us; speedup 1.0000x reference)
//
#include <hip/hip_runtime.h>
#include <math.h>

// VectorQuantizer: x (32768,64) f32, codebook (8192,64) f32, start/end/use_sk int scalars.
// Outputs concat: x_q_st (2097152 f32) | loss (1 f32) | indices (32768 stored as f32 values).
//
// Correctness strategy: replicate numpy fp32 rounding exactly.
//  - ||x||^2, ||c||^2: numpy pairwise-8 pattern, products rounded separately (no FMA).
//  - dot: 8 stride-8 accumulators, mul-then-add, combined ((t0+t1)+(t2+t3))+((t4+t5)+(t6+t7)).
//  - d = fl(fl(sx+sc_k) - 2*t); argmin first-occurrence (strict <, ascending k / chunk).

#define N_E    8192
#define EDIM   64
#define NTOK   32768
#define CHUNKS 8
#define CPC    (N_E / CHUNKS)       // 1024 codes per chunk
#define NELEM  (NTOK * EDIM)        // 2097152

// ---------------- k1: codebook squared norms (np.sum pairwise-8 replica) -------------
__global__ __launch_bounds__(256) void vq_sc(const float* __restrict__ cb,
                                             float* __restrict__ sc) {
#pragma clang fp contract(off)
  int r = blockIdx.x * 256 + threadIdx.x;
  const float* row = cb + (size_t)r * EDIM;
  float v[EDIM];
#pragma unroll
  for (int j = 0; j < EDIM / 4; ++j) {
    float4 f = ((const float4*)row)[j];
    v[4*j+0] = f.x; v[4*j+1] = f.y; v[4*j+2] = f.z; v[4*j+3] = f.w;
  }
  float a[8];
#pragma unroll
  for (int j = 0; j < 8; ++j) a[j] = v[j] * v[j];
#pragma unroll
  for (int i = 8; i < EDIM; i += 8)
#pragma unroll
    for (int j = 0; j < 8; ++j) a[j] += v[i+j] * v[i+j];
  sc[r] = ((a[0]+a[1]) + (a[2]+a[3])) + ((a[4]+a[5]) + (a[6]+a[7]));
}

// ---------------- k2: distances + per-chunk argmin -----------------------------------
// thread = token (x row in 64 VGPRs), blockIdx.y = code chunk.
// codebook row addresses are wave-uniform -> scalar loads expected.
__global__ __launch_bounds__(256, 4) void vq_dist(
    const float* __restrict__ x, const float* __restrict__ cb,
    const float* __restrict__ sc, float2* __restrict__ best,
    const int* __restrict__ p_start, const int* __restrict__ p_end) {
#pragma clang fp contract(off)
  int token = blockIdx.x * 256 + threadIdx.x;
  int chunk = blockIdx.y;
  const float* xr = x + (size_t)token * EDIM;
  float xv[EDIM];
#pragma unroll
  for (int j = 0; j < EDIM / 4; ++j) {
    float4 f = ((const float4*)xr)[j];
    xv[4*j+0] = f.x; xv[4*j+1] = f.y; xv[4*j+2] = f.z; xv[4*j+3] = f.w;
  }
  // sx = np.sum(x*x) pairwise-8 replica
  float a[8];
#pragma unroll
  for (int j = 0; j < 8; ++j) a[j] = xv[j] * xv[j];
#pragma unroll
  for (int i = 8; i < EDIM; i += 8)
#pragma unroll
    for (int j = 0; j < 8; ++j) a[j] += xv[i+j] * xv[i+j];
  float sx = ((a[0]+a[1]) + (a[2]+a[3])) + ((a[4]+a[5]) + (a[6]+a[7]));

  int s = *p_start, e = *p_end;
  int kbeg = chunk * CPC; if (kbeg < s) kbeg = s;
  int kend = chunk * CPC + CPC; if (kend > e) kend = e;

  float bestd = INFINITY;
  float besti = -1.0f;
  for (int k = kbeg; k < kend; ++k) {
    const float4* c4 = (const float4*)(cb + (size_t)k * EDIM);
    float t[8];
#pragma unroll
    for (int j = 0; j < 8; ++j) t[j] = 0.0f;   // 0 + fl(c*x) == fl(c*x), exact
#pragma unroll
    for (int h = 0; h < 2; ++h) {              // two halves of 32 to cap reg pressure
      float cv[32];
#pragma unroll
      for (int j = 0; j < 8; ++j) {
        float4 f = c4[h*8 + j];
        cv[4*j+0] = f.x; cv[4*j+1] = f.y; cv[4*j+2] = f.z; cv[4*j+3] = f.w;
      }
#pragma unroll
      for (int i = 0; i < 4; ++i)
#pragma unroll
        for (int j = 0; j < 8; ++j)
          t[j] += cv[i*8 + j] * xv[h*32 + i*8 + j];   // stride-8 accum pattern
    }
    float tt = ((t[0]+t[1]) + (t[2]+t[3])) + ((t[4]+t[5]) + (t[6]+t[7]));
    float d = (sx + sc[k]) - 2.0f * tt;
    if (d < bestd) { bestd = d; besti = (float)k; }  // strict <: first occurrence wins
  }
  best[(size_t)token * CHUNKS + chunk] = make_float2(bestd, besti);
}

// ---------------- k3: combine chunks, gather, x_q_st, loss partials ------------------
// wave = token (lane = element) for coalesced 256B row accesses.
__global__ __launch_bounds__(256) void vq_combine(
    const float* __restrict__ x, const float* __restrict__ cb,
    const float2* __restrict__ best, float* __restrict__ out_xq,
    float* __restrict__ out_idx, float* __restrict__ partial) {
  int tid  = threadIdx.x;
  int wv   = tid >> 6;
  int lane = tid & 63;
  int token = blockIdx.x * 4 + wv;

  float bd = INFINITY;
  float bi = -1.0f;
#pragma unroll
  for (int c = 0; c < CHUNKS; ++c) {          // ascending chunk + strict < == global
    float2 p = best[(size_t)token * CHUNKS + c];  // first-occurrence argmin
    if (p.x < bd) { bd = p.x; bi = p.y; }
  }
  int bidx = (int)bi;

  float q  = cb[(size_t)bidx * EDIM + lane];
  float xx = x[(size_t)token * EDIM + lane];
  float diff = q - xx;                         // fl(x_q - x)
  out_xq[(size_t)token * EDIM + lane] = xx + diff;  // fl(x + fl(x_q - x)) as reference
  if (lane == 0) out_idx[token] = bi;          // index as float value

  float l = diff * diff;
#pragma unroll
  for (int off = 32; off >= 1; off >>= 1) l += __shfl_down(l, off, 64);
  __shared__ float sdata[4];
  if (lane == 0) sdata[wv] = l;
  __syncthreads();
  if (tid == 0) partial[blockIdx.x] = (sdata[0] + sdata[1]) + (sdata[2] + sdata[3]);
}

// ---------------- k4: final loss reduction -------------------------------------------
__global__ __launch_bounds__(256) void vq_loss(const float* __restrict__ partial,
                                               float* __restrict__ out_loss) {
  int tid = threadIdx.x;
  float s = 0.0f;
  for (int i = tid; i < NTOK / 4; i += 256) s += partial[i];
#pragma unroll
  for (int off = 32; off >= 1; off >>= 1) s += __shfl_down(s, off, 64);
  __shared__ float sdata[4];
  if ((tid & 63) == 0) sdata[tid >> 6] = s;
  __syncthreads();
  if (tid == 0) {
    float total = (sdata[0] + sdata[1]) + (sdata[2] + sdata[3]);
    float m = total * (1.0f / (float)NELEM);   // /2^21: exact scaling
    out_loss[0] = m + 0.25f * m;               // codebook_loss + BETA*commitment
  }
}

// ---------------- launch -------------------------------------------------------------
extern "C" void kernel_launch(void* const* d_in, const int* in_sizes, int n_in,
                              void* d_out, int out_size, void* d_ws, size_t ws_size,
                              hipStream_t stream) {
  const float* x  = (const float*)d_in[0];
  const float* cb = (const float*)d_in[1];
  const int* p_start = (const int*)d_in[2];
  const int* p_end   = (const int*)d_in[3];

  float* ws = (float*)d_ws;
  float*  sc      = ws;                                  // 8192 floats
  float2* best    = (float2*)(ws + N_E);                 // 32768*8 float2 (2 MB)
  float*  partial = ws + N_E + (size_t)NTOK * CHUNKS * 2; // 8192 floats

  float* out      = (float*)d_out;
  float* out_xq   = out;                 // 2097152
  float* out_loss = out + NELEM;         // 1
  float* out_idx  = out + NELEM + 1;     // 32768

  vq_sc<<<N_E / 256, 256, 0, stream>>>(cb, sc);
  dim3 g2(NTOK / 256, CHUNKS);
  vq_dist<<<g2, 256, 0, stream>>>(x, cb, sc, best, p_start, p_end);
  vq_combine<<<NTOK / 4, 256, 0, stream>>>(x, cb, best, out_xq, out_idx, partial);
  vq_loss<<<1, 256, 0, stream>>>(partial, out_loss);
}